// Round 21
// baseline (210.459 us; speedup 1.0000x reference)
//
#include <hip/hip_runtime.h>
#include <stdint.h>

#define FD    512
#define SEQ   2048
#define NHALF 8192
#define NTOT  16384
#define QKVN  1536

typedef unsigned short u16;
typedef __attribute__((ext_vector_type(8))) short short8;
typedef __attribute__((ext_vector_type(4))) float f32x4;
typedef __attribute__((ext_vector_type(16))) float f32x16;

__device__ __forceinline__ u16 f2bf(float f){
  union { float f; uint32_t i; } v; v.f = f;
  uint32_t r = v.i + 0x7FFFu + ((v.i >> 16) & 1u);
  return (u16)(r >> 16);
}

__device__ __forceinline__ float bf2f(u16 u){
  union { uint32_t i; float f; } v; v.i = ((uint32_t)u) << 16; return v.f;
}

__device__ __forceinline__ void gload_lds16(const void* g, void* l){
  __builtin_amdgcn_global_load_lds((const __attribute__((address_space(1))) void*)g,
                                   (__attribute__((address_space(3))) void*)l, 16, 0, 0);
}

__device__ __forceinline__ f32x4 mfma16(short8 a, short8 b, f32x4 c){
  return __builtin_amdgcn_mfma_f32_16x16x32_bf16(a, b, c, 0, 0, 0);
}

__device__ __forceinline__ f32x16 mfma32(short8 a, short8 b, f32x16 c){
  return __builtin_amdgcn_mfma_f32_32x32x16_bf16(a, b, c, 0, 0, 0);
}

__device__ __forceinline__ uint32_t cvtpk(float lo, float hi){
  uint32_t r; asm("v_cvt_pk_bf16_f32 %0, %1, %2" : "=v"(r) : "v"(lo), "v"(hi)); return r;
}

// exchange low/high 32-lane halves between two VGPRs (VALU, not LDS pipe)
__device__ __forceinline__ void plswap(uint32_t &a, uint32_t &b){
  asm volatile("v_permlane32_swap_b32 %0, %1" : "+v"(a), "+v"(b));
}

// single-instruction 2^x (v_exp_f32); exp2f() without fast-math is a slow OCML poly
__device__ __forceinline__ float fexp2(float x){
  float r; asm("v_exp_f32 %0, %1" : "=v"(r) : "v"(x)); return r;
}

// ---- weight convert + transpose via LDS tile: wt[mat][n][k] = bf16(w[k][n]) ----
__global__ __launch_bounds__(256) void wconv_kernel(
    const float* __restrict__ w0, const float* __restrict__ w1,
    const float* __restrict__ w2, const float* __restrict__ w3,
    const float* __restrict__ w4, const float* __restrict__ w5,
    const float* __restrict__ w6, const float* __restrict__ w7,
    u16* __restrict__ out)
{
  int mat = blockIdx.x >> 6;
  const float* w = w0;
  switch (mat){ case 1: w=w1; break; case 2: w=w2; break; case 3: w=w3; break;
                case 4: w=w4; break; case 5: w=w5; break; case 6: w=w6; break;
                case 7: w=w7; break; default: break; }
  int tile = blockIdx.x & 63;
  int k0 = (tile >> 3) << 6, n0 = (tile & 7) << 6;

  __shared__ float lt[64][65];
  int tid = threadIdx.x;
  int tr = tid >> 4, tc = (tid & 15) << 2;
  #pragma unroll
  for (int p = 0; p < 4; p++){
    int k = p * 16 + tr;
    float4 v = *(const float4*)&w[(size_t)(k0 + k) * 512 + n0 + tc];
    lt[k][tc] = v.x; lt[k][tc + 1] = v.y; lt[k][tc + 2] = v.z; lt[k][tc + 3] = v.w;
  }
  __syncthreads();
  int n = tid >> 2, kc = (tid & 3) << 4;
  u16 buf[16];
  #pragma unroll
  for (int j = 0; j < 16; j++) buf[j] = f2bf(lt[kc + j][n]);
  u16* dst = out + ((size_t)mat << 18) + (size_t)(n0 + n) * 512 + k0 + kc;
  *(short8*)dst       = *(const short8*)(buf);
  *(short8*)(dst + 8) = *(const short8*)(buf + 8);
}

__global__ __launch_bounds__(256) void biascat_kernel(
    const float* __restrict__ bq, const float* __restrict__ bk,
    const float* __restrict__ bv, float* __restrict__ o)
{
  int i = blockIdx.x * 256 + threadIdx.x;      // grid 6 -> 0..1535
  if (i < 512) o[i] = bq[i];
  else if (i < 1024) o[i] = bk[i - 512];
  else o[i] = bv[i - 1024];
}

// ---- layernorm, wave-per-row: 4 rows/block, no LDS, no barriers ----
template<bool INBF>
__global__ __launch_bounds__(256) void ln_kernel(
    const void* __restrict__ xa, const void* __restrict__ xb,
    const float* __restrict__ ga, const float* __restrict__ ba,
    const float* __restrict__ gb, const float* __restrict__ bb,
    u16* __restrict__ out)
{
  int row = (blockIdx.x << 2) + (threadIdx.x >> 6);
  int ln = threadIdx.x & 63;
  const void* xp; const float* g; const float* bi; int rl;
  if (row < NHALF){ xp = xa; g = ga; bi = ba; rl = row; }
  else            { xp = xb; g = gb; bi = bb; rl = row - NHALF; }
  int c = ln << 3;
  float d[8];
  if (INBF){
    short8 s8 = *(const short8*)((const u16*)xp + (size_t)rl * FD + c);
    #pragma unroll
    for (int j = 0; j < 8; j++) d[j] = bf2f((u16)s8[j]);
  } else {
    const float* x = (const float*)xp + (size_t)rl * FD + c;
    float4 v0 = *(const float4*)x;
    float4 v1 = *(const float4*)(x + 4);
    d[0]=v0.x; d[1]=v0.y; d[2]=v0.z; d[3]=v0.w;
    d[4]=v1.x; d[5]=v1.y; d[6]=v1.z; d[7]=v1.w;
  }
  float s = (d[0] + d[1]) + (d[2] + d[3]) + (d[4] + d[5]) + (d[6] + d[7]);
  #pragma unroll
  for (int o = 32; o; o >>= 1) s += __shfl_xor(s, o, 64);
  float mu = s * (1.0f / 512.0f);
  float q = 0.f;
  #pragma unroll
  for (int j = 0; j < 8; j++){ d[j] -= mu; q += d[j] * d[j]; }
  #pragma unroll
  for (int o = 32; o; o >>= 1) q += __shfl_xor(q, o, 64);
  float rs = rsqrtf(q * (1.0f / 512.0f) + 1e-6f);
  float4 g0 = *(const float4*)&g[c],  g1 = *(const float4*)&g[c + 4];
  float4 b0 = *(const float4*)&bi[c], b1 = *(const float4*)&bi[c + 4];
  float gg[8] = {g0.x, g0.y, g0.z, g0.w, g1.x, g1.y, g1.z, g1.w};
  float bbv[8] = {b0.x, b0.y, b0.z, b0.w, b1.x, b1.y, b1.z, b1.w};
  u16 o8[8];
  #pragma unroll
  for (int j = 0; j < 8; j++) o8[j] = f2bf(d[j] * rs * gg[j] + bbv[j]);
  *(short8*)&out[(size_t)row * FD + c] = *(const short8*)o8;
}

// ---- GEMM: C = A[M,K] @ Bt[N,K]^T + bias (+res), 128x128 tile, BK=32 ----
template<bool RELU, bool OUT_BF16, bool HAS_RES, bool RES_BF16, bool QKV_VT>
__global__ __launch_bounds__(256) void gemm_bt(
    const u16* __restrict__ A,
    const u16* __restrict__ BtLo, const u16* __restrict__ BtHi,
    const float* __restrict__ biasLo, const float* __restrict__ biasHi,
    const void* __restrict__ resLo, const void* __restrict__ resHi,
    void* __restrict__ outp, u16* __restrict__ vtp,
    int M, int N, int K, int halfM)
{
  __shared__ __align__(16) u16 lA[3][64 * 64];
  __shared__ __align__(16) u16 lB[3][64 * 64];
  int nwg = gridDim.x;
  int bid = (blockIdx.x & 7) * (nwg >> 3) + (blockIdx.x >> 3);
  int nTN = N >> 7;
  int bm = bid / nTN, bn = bid - bm * nTN;
  int rowBase = bm << 7, colBase = bn << 7;
  bool inLo = rowBase < halfM;
  const u16* Bt = inLo ? BtLo : BtHi;
  const float* bias = inLo ? biasLo : biasHi;
  const void* res = inLo ? resLo : resHi;
  int rowLocalBase = inLo ? rowBase : rowBase - halfM;

  int tid = threadIdx.x, wv = tid >> 6, ln = tid & 63;
  int g = ln >> 4, la = ln & 15;

  f32x4 acc[4][4];
  #pragma unroll
  for (int m = 0; m < 4; m++)
    #pragma unroll
    for (int n = 0; n < 4; n++) acc[m][n] = (f32x4){0.f, 0.f, 0.f, 0.f};

  int r   = tid >> 3;
  int sl  = (tid & 7) ^ (r & 7);
  int shalf = sl >> 2, sk8 = (sl & 3) << 3;
  const u16* gA0 = A  + (size_t)(rowBase + r + shalf * 64) * K + sk8;
  const u16* gB0 = Bt + (size_t)(colBase + r + shalf * 64) * K + sk8;
  const size_t row32 = (size_t)32 * K;

  int caA = (((wv >> 1) << 5) + (g << 3)) ^ ((la & 7) << 3);
  int caB = (((wv & 1) << 5) + (g << 3)) ^ ((la & 7) << 3);

  int arow = (wv >> 1) << 6, bcol = (wv & 1) << 6;

  #define STAGE(buf, kt) do { \
    gload_lds16(gA0 + (kt), (char*)lA[buf] + wv * 1024); \
    gload_lds16(gA0 + (kt) + row32, (char*)lA[buf] + 4096 + wv * 1024); \
    gload_lds16(gB0 + (kt), (char*)lB[buf] + wv * 1024); \
    gload_lds16(gB0 + (kt) + row32, (char*)lB[buf] + 4096 + wv * 1024); } while (0)

  int nK = K >> 5;
  STAGE(0, 0);
  STAGE(1, 32);

  for (int i = 0; i < nK; i++){
    if (i < nK - 1) asm volatile("s_waitcnt vmcnt(4)" ::: "memory");
    else            asm volatile("s_waitcnt vmcnt(0)" ::: "memory");
    __builtin_amdgcn_s_barrier();
    __builtin_amdgcn_sched_barrier(0);
    int cur = i % 3;
    if (i + 2 < nK) STAGE((i + 2) % 3, (i + 2) << 5);
    short8 af[4], bfr[4];
    #pragma unroll
    for (int m = 0; m < 4; m++)
      af[m] = *(const short8*)&lA[cur][((m << 4) + la) * 64 + caA];
    #pragma unroll
    for (int n = 0; n < 4; n++)
      bfr[n] = *(const short8*)&lB[cur][((n << 4) + la) * 64 + caB];
    #pragma unroll
    for (int m = 0; m < 4; m++)
      #pragma unroll
      for (int n = 0; n < 4; n++)
        acc[m][n] = mfma16(af[m], bfr[n], acc[m][n]);
  }
  #undef STAGE

  #pragma unroll
  for (int n = 0; n < 4; n++){
    int col = colBase + bcol + (n << 4) + la;
    float bv = bias[col];
    #pragma unroll
    for (int m = 0; m < 4; m++){
      int rowT = arow + (m << 4) + (g << 2);
      float v4[4];
      #pragma unroll
      for (int rr = 0; rr < 4; rr++){
        float v = acc[m][n][rr] + bv;
        if (RELU) v = fmaxf(v, 0.f);
        if (HAS_RES){
          size_t ri = (size_t)(rowLocalBase + rowT + rr) * N + col;
          if (RES_BF16) v += bf2f(((const u16*)res)[ri]);
          else          v += ((const float*)res)[ri];
        }
        v4[rr] = v;
      }
      if (QKV_VT && col >= 1024){
        int cv = col - 1024;
        int rowA = rowBase + rowT;
        int slab = ((rowA >= NHALF) ? 32 : 0) + (((rowA >> 11) & 3) << 3) + (cv >> 6);
        uint2 w; w.x = cvtpk(v4[0], v4[1]); w.y = cvtpk(v4[2], v4[3]);
        *(uint2*)&vtp[(size_t)slab * 131072 + (size_t)(cv & 63) * 2048 + (rowA & 2047)] = w;
      } else {
        #pragma unroll
        for (int rr = 0; rr < 4; rr++){
          if (OUT_BF16) ((u16*)outp)[(size_t)(rowBase + rowT + rr) * N + col] = f2bf(v4[rr]);
          else ((float*)outp)[(size_t)(rowBase + rowT + rr) * N + col] = v4[rr];
        }
      }
    }
  }
}

// ---- flash cross-attention, 32x32 MFMA + permlane P hand-off ----
// 8 waves x 32 q (q = lane&31), Q=256/block. K/Vt LDS double-buffers (32KB).
// Swapped QK^T (mfma32(K,Q)): lane holds S[key][q=l&31]. P stays in REGISTERS:
// cvtpk pairs + v_permlane32_swap build PV A-frags (no P LDS round-trip).
__global__ __launch_bounds__(512, 4) void attn_kernel(
    const u16* __restrict__ qkv, const u16* __restrict__ vt, u16* __restrict__ fb)
{
  int l_ = (blockIdx.x & 7) * 64 + (blockIdx.x >> 3);
  int qt = l_ & 7;                // 0..7
  int h  = (l_ >> 3) & 7;         // 0..7
  int z  = l_ >> 6;               // dir*4 + b
  int dir = z >> 2, b = z & 3;
  int qRow0  = dir * NHALF + b * SEQ + qt * 256;
  int kvRow0 = (dir ^ 1) * NHALF + b * SEQ;
  int colQ = h * 64;

  __shared__ __align__(16) u16 lK[2][64 * 64];
  __shared__ __align__(16) u16 lVt[2][64 * 64];

  int tid = threadIdx.x, wv = tid >> 6, ln = tid & 63;
  int q5 = ln & 31, hi = ln >> 5;

  int srow = tid >> 3;                         // 0..63
  int soff = ((tid & 7) ^ (srow & 7)) * 8;

  const float CEXP = 0.18033688f;   // 0.125 * log2(e)

  // frag u16 indices (blk in {0,1} = key-block or d-block, ks = k-slice 0..3)
  int fsw = (q5 & 7) << 3;
  int fidx[2][4];
  #pragma unroll
  for (int blk = 0; blk < 2; blk++)
    #pragma unroll
    for (int ks = 0; ks < 4; ks++)
      fidx[blk][ks] = (blk * 32 + q5) * 64 + ((ks * 16 + hi * 8) ^ fsw);

  const u16* vtbase = vt + (size_t)((dir ^ 1) * 32 + b * 8 + h) * 131072;
  const u16* kp0 = qkv + (size_t)(kvRow0 + srow) * QKVN + 512 + colQ + soff;
  const u16* vp0 = vtbase + (size_t)srow * 2048 + soff;

  char* dK0 = (char*)lK[0] + wv * 1024;
  char* dV0 = (char*)lVt[0] + wv * 1024;
  const u16* lKf = &lK[0][0];
  const u16* lVf = &lVt[0][0];

  // Q frags direct from global (B-operand: col q=l&31, k = ks*16 + hi*8 + j)
  const u16* qp = qkv + (size_t)(qRow0 + wv * 32 + q5) * QKVN + colQ + hi * 8;
  short8 qf0 = *(const short8*)(qp);
  short8 qf1 = *(const short8*)(qp + 16);
  short8 qf2 = *(const short8*)(qp + 32);
  short8 qf3 = *(const short8*)(qp + 48);

  // stage K(0), Vt(0)
  gload_lds16(kp0, dK0);
  gload_lds16(vp0, dV0);
  kp0 += (size_t)64 * QKVN; vp0 += 64;
  __syncthreads();

  f32x16 acc0, acc1;
  #pragma unroll
  for (int j = 0; j < 16; j++){ acc0[j] = 0.f; acc1[j] = 0.f; }
  float acc_ls = 0.f;
  float m_l = 0.f;

  int cb = 0;
  for (int t = 0; t < 32; t++){
    if (t < 31){
      int nb = cb ^ 8192;
      gload_lds16(kp0, dK0 + nb);
      gload_lds16(vp0, dV0 + nb);
      kp0 += (size_t)64 * QKVN; vp0 += 64;
    }
    const u16* lk = (const u16*)((const char*)lKf + cb);
    const u16* lv = (const u16*)((const char*)lVf + cb);

    // QK^T: s[kb] = K(kb) x Q, lane holds col q=l&31, 16 key-rows per kb
    f32x16 s0, s1;
    s0 = mfma32(*(const short8*)&lk[fidx[0][0]], qf0, acc0 * 0.f);
    s0 = mfma32(*(const short8*)&lk[fidx[0][1]], qf1, s0);
    s0 = mfma32(*(const short8*)&lk[fidx[0][2]], qf2, s0);
    s0 = mfma32(*(const short8*)&lk[fidx[0][3]], qf3, s0);
    s1 = mfma32(*(const short8*)&lk[fidx[1][0]], qf0, acc0 * 0.f);
    s1 = mfma32(*(const short8*)&lk[fidx[1][1]], qf1, s1);
    s1 = mfma32(*(const short8*)&lk[fidx[1][2]], qf2, s1);
    s1 = mfma32(*(const short8*)&lk[fidx[1][3]], qf3, s1);

    // row max over 64 keys: in-lane 32 + partner half
    float m0;
    {
      float a0 = fmaxf(fmaxf(s0[0], s0[1]), fmaxf(s0[2], s0[3]));
      float a1 = fmaxf(fmaxf(s0[4], s0[5]), fmaxf(s0[6], s0[7]));
      float a2 = fmaxf(fmaxf(s0[8], s0[9]), fmaxf(s0[10], s0[11]));
      float a3 = fmaxf(fmaxf(s0[12], s0[13]), fmaxf(s0[14], s0[15]));
      float b0 = fmaxf(fmaxf(s1[0], s1[1]), fmaxf(s1[2], s1[3]));
      float b1 = fmaxf(fmaxf(s1[4], s1[5]), fmaxf(s1[6], s1[7]));
      float b2 = fmaxf(fmaxf(s1[8], s1[9]), fmaxf(s1[10], s1[11]));
      float b3 = fmaxf(fmaxf(s1[12], s1[13]), fmaxf(s1[14], s1[15]));
      m0 = fmaxf(fmaxf(fmaxf(a0, a1), fmaxf(a2, a3)),
                 fmaxf(fmaxf(b0, b1), fmaxf(b2, b3)));
      m0 = fmaxf(m0, __shfl_xor(m0, 32, 64));
      m0 *= CEXP;
    }
    if (t == 0) m_l = m0;

    // eager P with old m_l; per kb: cvtpk pairs -> permlane swaps -> A-frags -> PV
    float ps = 0.f;
    #define PKB(SK, KS0, KS1) do { \
      float p[16]; \
      _Pragma("unroll") \
      for (int j = 0; j < 16; j++){ p[j] = fexp2(fmaf(SK[j], CEXP, -m_l)); ps += p[j]; } \
      uint32_t A0 = cvtpk(p[0], p[1]),  A1 = cvtpk(p[2], p[3]); \
      uint32_t B0 = cvtpk(p[4], p[5]),  B1 = cvtpk(p[6], p[7]); \
      uint32_t C0 = cvtpk(p[8], p[9]),  C1 = cvtpk(p[10], p[11]); \
      uint32_t D0 = cvtpk(p[12], p[13]), D1 = cvtpk(p[14], p[15]); \
      plswap(A0, B0); plswap(A1, B1); \
      plswap(C0, D0); plswap(C1, D1); \
      union { uint32_t u[4]; short8 s8; } fa, fb_; \
      fa.u[0] = A0; fa.u[1] = A1; fa.u[2] = B0; fa.u[3] = B1; \
      fb_.u[0] = C0; fb_.u[1] = C1; fb_.u[2] = D0; fb_.u[3] = D1; \
      short8 vA0 = *(const short8*)&lv[fidx[0][KS0]]; \
      short8 vA1 = *(const short8*)&lv[fidx[1][KS0]]; \
      short8 vB0 = *(const short8*)&lv[fidx[0][KS1]]; \
      short8 vB1 = *(const short8*)&lv[fidx[1][KS1]]; \
      acc0 = mfma32(fa.s8, vA0, acc0); \
      acc1 = mfma32(fa.s8, vA1, acc1); \
      acc0 = mfma32(fb_.s8, vB0, acc0); \
      acc1 = mfma32(fb_.s8, vB1, acc1); \
    } while (0)

    PKB(s0, 0, 1);
    PKB(s1, 2, 3);
    #undef PKB
    acc_ls += ps;

    // defer-max: rescale only if some row grew > 8 (log2 domain)
    if (!__all(m0 <= m_l + 8.f)){
      float mn = fmaxf(m_l, m0);
      float a0 = fexp2(m_l - mn);
      m_l = mn;
      acc_ls *= a0;
      #pragma unroll
      for (int reg = 0; reg < 16; reg++){
        int qr = (reg & 3) + 8 * (reg >> 2) + 4 * hi;
        float ar = __shfl(a0, qr, 64);
        acc0[reg] *= ar;
        acc1[reg] *= ar;
      }
    }

    cb ^= 8192;
    __syncthreads();
  }

  // epilogue: full row sum = own-half + partner-half; per-reg q-row lookup
  float lsum = acc_ls + __shfl_xor(acc_ls, 32, 64);
  float rcp = 1.0f / lsum;
  #pragma unroll
  for (int reg = 0; reg < 16; reg++){
    int qr = (reg & 3) + 8 * (reg >> 2) + 4 * hi;
    float rl = __shfl(rcp, qr, 64);
    size_t row = (size_t)(qRow0 + wv * 32 + qr) * FD + colQ + q5;
    fb[row]      = f2bf(acc0[reg] * rl);
    fb[row + 32] = f2bf(acc1[reg] * rl);
  }
}

extern "C" void kernel_launch(void* const* d_in, const int* in_sizes, int n_in,
                              void* d_out, int out_size, void* d_ws, size_t ws_size,
                              hipStream_t stream)
{
  const float* t1   = (const float*)d_in[0];
  const float* t2   = (const float*)d_in[1];
  const float* ln1g = (const float*)d_in[2];
  const float* ln1b = (const float*)d_in[3];
  const float* ln2g = (const float*)d_in[4];
  const float* ln2b = (const float*)d_in[5];
  const float* Wq   = (const float*)d_in[6];
  const float* bq   = (const float*)d_in[7];
  const float* Wk   = (const float*)d_in[8];
  const float* bk   = (const float*)d_in[9];
  const float* Wv   = (const float*)d_in[10];
  const float* bv   = (const float*)d_in[11];
  const float* Wfc  = (const float*)d_in[12];
  const float* bfc  = (const float*)d_in[13];
  const float* f1lg = (const float*)d_in[14];
  const float* f1lb = (const float*)d_in[15];
  const float* W11  = (const float*)d_in[16];
  const float* b11  = (const float*)d_in[17];
  const float* W12  = (const float*)d_in[18];
  const float* b12  = (const float*)d_in[19];
  const float* f2lg = (const float*)d_in[20];
  const float* f2lb = (const float*)d_in[21];
  const float* W21  = (const float*)d_in[22];
  const float* b21  = (const float*)d_in[23];
  const float* W22  = (const float*)d_in[24];
  const float* b22  = (const float*)d_in[25];

  char* ws = (char*)d_ws;
  const size_t MB = 1024 * 1024;
  u16* wt     = (u16*)ws;                  // 8 x [512,512] bf16 (transposed)
  u16* tln    = (u16*)(ws + 4 * MB);       // [16384,512]   (dead after QKV GEMM)
  u16* qkv    = (u16*)(ws + 20 * MB);      // [16384,1536]  (dead after attn)
  u16* fbuf   = (u16*)(ws + 68 * MB);      // [16384,512]
  float* bqkv = (float*)(ws + 84 * MB);    // [1536]
  u16* vtb    = (u16*)(ws + 85 * MB);      // V^T slabs [64][64][2048] (16 MB)
  u16* xln    = tln;                       // reuse after attn
  u16* hb     = qkv;                       // ff1 out: first 16MB of dead qkv
  u16* xb     = (u16*)(ws + 36 * MB);      // x as bf16: next 16MB of dead qkv
  float* out  = (float*)d_out;

  wconv_kernel<<<512, 256, 0, stream>>>(Wq, Wk, Wv, Wfc, W11, W12, W21, W22, wt);
  biascat_kernel<<<6, 256, 0, stream>>>(bq, bk, bv, bqkv);
  ln_kernel<false><<<4096, 256, 0, stream>>>(t1, t2, ln1g, ln1b, ln2g, ln2b, tln);
  gemm_bt<false, true, false, false, true><<<1536, 256, 0, stream>>>(
      tln, wt, wt, bqkv, bqkv, nullptr, nullptr, qkv, vtb, NTOT, QKVN, FD, NTOT);
  attn_kernel<<<512, 512, 0, stream>>>(qkv, vtb, fbuf);
  gemm_bt<false, true, true, false, false><<<512, 256, 0, stream>>>(
      fbuf, wt + 3 * 262144, wt + 3 * 262144, bfc, bfc, t1, t2, xb, nullptr, NTOT, FD, FD, NHALF);
  ln_kernel<true><<<4096, 256, 0, stream>>>(xb, xb + (size_t)NHALF * FD,
      f1lg, f1lb, f2lg, f2lb, xln);
  gemm_bt<true, true, false, false, false><<<512, 256, 0, stream>>>(
      xln, wt + 4 * 262144, wt + 6 * 262144, b11, b21, nullptr, nullptr, hb, nullptr, NTOT, FD, FD, NHALF);
  gemm_bt<false, false, true, true, false><<<512, 256, 0, stream>>>(
      hb, wt + 5 * 262144, wt + 7 * 262144, b12, b22, xb, xb + (size_t)NHALF * FD,
      out, nullptr, NTOT, FD, FD, NHALF);
}